// Round 4
// baseline (170.292 us; speedup 1.0000x reference)
//
#include <hip/hip_runtime.h>
#include <hip/hip_bf16.h>
#include <cstdint>

#define B_ 2048
#define N_ 4096
#define D_ 256
#define P_ 100
#define K_ 30
#define INVT 5.0f
#define NTILE 64              // 64x64 wave tiles over N_=4096
#define NJOBS (NTILE * (NTILE + 1) / 2)  // 2080

typedef __attribute__((ext_vector_type(8))) short bf16x8;
typedef __attribute__((ext_vector_type(4))) float f32x4;
typedef __attribute__((ext_vector_type(4))) unsigned short us4;

__device__ __forceinline__ float waveReduceSum(float v) {
#pragma unroll
  for (int off = 32; off > 0; off >>= 1) v += __shfl_xor(v, off, 64);
  return v;
}

__device__ __forceinline__ unsigned short f2bf(float f) {
  __hip_bfloat16 h = __float2bfloat16(f);
  return *reinterpret_cast<unsigned short*>(&h);
}
__device__ __forceinline__ float bf2f(unsigned short u) {
  return __uint_as_float(((unsigned int)u) << 16);
}

// ---- K1: block 0 = zero sums/ticket + hist/concat; 1..100 = proto_dist row; 101..612 = row-norm+pos ----
__global__ __launch_bounds__(256) void prep_kernel(
    const float* __restrict__ x, const float* __restrict__ xa, const float* __restrict__ pw,
    const int* __restrict__ hq1, const int* __restrict__ hq2, int* __restrict__ hq,
    int* __restrict__ cnt, float* __restrict__ pd, __hip_bfloat16* __restrict__ outb,
    float* __restrict__ sums) {
  __shared__ int c[P_];
  __shared__ float s4[4];
  int t = threadIdx.x, lane = t & 63, wv = t >> 6;
  int bx = blockIdx.x;
  if (bx == 0) {
    if (t < 2) sums[t] = 0.f;
    if (t == 2) ((int*)sums)[2] = 0;  // ticket
    if (t < P_) c[t] = 0;
    __syncthreads();
    for (int i = t; i < N_; i += 256) {
      int q = (i < B_) ? hq1[i] : hq2[i - B_];
      hq[i] = q;
      atomicAdd(&c[q], 1);
    }
    __syncthreads();
    if (t < P_) cnt[t] = c[t];
  } else if (bx <= P_) {
    int q = bx - 1;
    float4 aq = ((const float4*)(pw + q * D_))[lane];
    float ssq = waveReduceSum(aq.x * aq.x + aq.y * aq.y + aq.z * aq.z + aq.w * aq.w);
    float qinv = 1.f / fmaxf(sqrtf(ssq), 1e-12f);
    for (int r = wv; r < P_; r += 4) {
      float4 b = ((const float4*)(pw + r * D_))[lane];
      float s = aq.x * b.x + aq.y * b.y + aq.z * b.z + aq.w * b.w;
      float n = b.x * b.x + b.y * b.y + b.z * b.z + b.w * b.w;
      s = waveReduceSum(s);
      n = waveReduceSum(n);
      if (lane == 0) pd[q * P_ + r] = s * qinv / fmaxf(sqrtf(n), 1e-12f);
    }
  } else {
    int i = (bx - 101) * 4 + wv;
    float4 a = ((const float4*)(x + i * D_))[lane];
    float ss = waveReduceSum(a.x * a.x + a.y * a.y + a.z * a.z + a.w * a.w);
    float inv1 = 1.f / fmaxf(sqrtf(ss), 1e-12f);
    float o1x = a.x * inv1, o1y = a.y * inv1, o1z = a.z * inv1, o1w = a.w * inv1;
    us4 p1; p1[0] = f2bf(o1x); p1[1] = f2bf(o1y); p1[2] = f2bf(o1z); p1[3] = f2bf(o1w);
    ((us4*)(outb + i * D_))[lane] = p1;
    float4 b = ((const float4*)(xa + i * D_))[lane];
    float ss2 = waveReduceSum(b.x * b.x + b.y * b.y + b.z * b.z + b.w * b.w);
    float inv2 = 1.f / fmaxf(sqrtf(ss2), 1e-12f);
    float o2x = b.x * inv2, o2y = b.y * inv2, o2z = b.z * inv2, o2w = b.w * inv2;
    us4 p2; p2[0] = f2bf(o2x); p2[1] = f2bf(o2y); p2[2] = f2bf(o2z); p2[3] = f2bf(o2w);
    ((us4*)(outb + (B_ + i) * D_))[lane] = p2;
    float d = waveReduceSum(o1x * o2x + o1y * o2y + o1z * o2z + o1w * o2w);
    if (lane == 0) s4[wv] = d;
    __syncthreads();
    if (t == 0) atomicAdd(&sums[1], s4[0] + s4[1] + s4[2] + s4[3]);
  }
}

// ---- K2: per-row Gtab[i][p] (bf16) = member ? reweight : 0 ----
__global__ void gtab_kernel(const int* __restrict__ hq, const int* __restrict__ cnt,
                            const float* __restrict__ pd, const int* __restrict__ nq1,
                            const int* __restrict__ nq2, unsigned short* __restrict__ gtabh) {
  __shared__ unsigned char memb[4][104];
  int wv = threadIdx.x >> 6, lane = threadIdx.x & 63;
  int i = blockIdx.x * 4 + wv;
  int q = hq[i];
  if (lane < 52) { memb[wv][lane * 2] = 0; memb[wv][lane * 2 + 1] = 0; }
  __syncthreads();
  const int* nrow = (i < B_) ? (nq1 + i * K_) : (nq2 + (i - B_) * K_);
  if (lane < K_) memb[wv][nrow[lane]] = 1;
  __syncthreads();

  int p0 = lane, p1 = lane + 64;
  bool has1 = (p1 < P_);
  float v0 = pd[q * P_ + p0];
  int m0 = cnt[p0] - (p0 == q ? 1 : 0);
  float v1 = 0.f; int m1 = 0;
  if (has1) { v1 = pd[q * P_ + p1]; m1 = cnt[p1] - (p1 == q ? 1 : 0); }

  float mn = 1e30f, mx = -1e30f;
  if (m0 > 0) { mn = fminf(mn, v0); mx = fmaxf(mx, v0); }
  if (has1 && m1 > 0) { mn = fminf(mn, v1); mx = fmaxf(mx, v1); }
#pragma unroll
  for (int off = 32; off > 0; off >>= 1) {
    mn = fminf(mn, __shfl_xor(mn, off, 64));
    mx = fmaxf(mx, __shfl_xor(mx, off, 64));
  }
  float rmin = fminf(0.f, mn);
  float rmax = fmaxf(rmin, mx);
  float inv = 1.f / (rmax - rmin);
  float r0 = (v0 - rmin) * inv, r1 = (v1 - rmin) * inv;
  float s1 = (m0 > 0 ? (float)m0 * r0 : 0.f) + ((has1 && m1 > 0) ? (float)m1 * r1 : 0.f);
  s1 = waveReduceSum(s1);
  float mu = s1 / (float)N_;
  float ss = (m0 > 0 ? (float)m0 * (r0 - mu) * (r0 - mu) : 0.f) +
             ((has1 && m1 > 0) ? (float)m1 * (r1 - mu) * (r1 - mu) : 0.f);
  ss = waveReduceSum(ss);
  ss += mu * mu;
  float var = ss / (float)(N_ - 1);
  float i2v = 1.f / (2.f * var);
  float g0 = memb[wv][p0] ? __expf((r0 - mu) * (r0 - mu) * i2v) : 0.f;
  gtabh[i * P_ + p0] = f2bf(g0);
  if (has1) {
    float g1 = memb[wv][p1] ? __expf((r1 - mu) * (r1 - mu) * i2v) : 0.f;
    gtabh[i * P_ + p1] = f2bf(g1);
  }
}

// ---- K3: one wave = one 64x64 triangle tile, no LDS, direct-global MFMA frags ----
__global__ __launch_bounds__(64) void tot_kernel(
    const __hip_bfloat16* __restrict__ outb, const unsigned short* __restrict__ gtabh,
    const int* __restrict__ hq, float* __restrict__ sums, float* __restrict__ out) {
  const int lane = threadIdx.x;
  const int r16 = lane & 15, k8 = lane >> 4;

  // triangle decode: id -> (ti, tj), ti <= tj
  int rem = blockIdx.x, ti = 0;
  while (rem >= NTILE - ti) { rem -= NTILE - ti; ++ti; }
  const int tj = ti + rem;
  const bool diag = (ti == tj);
  const int i0 = ti * 64, j0 = tj * 64;

  const __hip_bfloat16* Ab = outb + (i0 + r16) * D_ + k8 * 8;
  const __hip_bfloat16* Bb = outb + (j0 + r16) * D_ + k8 * 8;

  f32x4 acc[4][4] = {};
  bf16x8 a[2][4], b[2][4];
#pragma unroll
  for (int m = 0; m < 4; ++m) {
    a[0][m] = *(const bf16x8*)(Ab + m * 16 * D_);
    b[0][m] = *(const bf16x8*)(Bb + m * 16 * D_);
  }
#pragma unroll
  for (int kk = 0; kk < 8; ++kk) {
    const int cur = kk & 1, nxt = cur ^ 1;
    if (kk < 7) {
#pragma unroll
      for (int m = 0; m < 4; ++m) {
        a[nxt][m] = *(const bf16x8*)(Ab + m * 16 * D_ + (kk + 1) * 32);
        b[nxt][m] = *(const bf16x8*)(Bb + m * 16 * D_ + (kk + 1) * 32);
      }
    }
#pragma unroll
    for (int m = 0; m < 4; ++m)
#pragma unroll
      for (int n = 0; n < 4; ++n)
        acc[m][n] = __builtin_amdgcn_mfma_f32_16x16x32_bf16(a[cur][m], b[cur][n], acc[m][n], 0, 0, 0);
  }

  // epilogue: hq + weight gathers straight from L2-resident tables
  int4 hi4[4];
#pragma unroll
  for (int m = 0; m < 4; ++m) hi4[m] = *(const int4*)(hq + i0 + m * 16 + k8 * 4);
  int hj[4];
#pragma unroll
  for (int n = 0; n < 4; ++n) hj[n] = hq[j0 + n * 16 + r16];

  float local = 0.f;
  if (diag) {
#pragma unroll
    for (int m = 0; m < 4; ++m) {
#pragma unroll
      for (int n = 0; n < 4; ++n) {
#pragma unroll
        for (int r = 0; r < 4; ++r) {
          int il = m * 16 + k8 * 4 + r;
          int jl = n * 16 + r16;
          float e = __expf(acc[m][n][r] * INVT);
          float wv = bf2f(gtabh[(i0 + il) * P_ + hj[n]]);
          if (il != jl) local += wv * e;
        }
      }
    }
  } else {
#pragma unroll
    for (int m = 0; m < 4; ++m) {
#pragma unroll
      for (int n = 0; n < 4; ++n) {
#pragma unroll
        for (int r = 0; r < 4; ++r) {
          int i = i0 + m * 16 + k8 * 4 + r;
          int j = j0 + n * 16 + r16;
          float e = __expf(acc[m][n][r] * INVT);
          float wv = bf2f(gtabh[i * P_ + hj[n]]);
          int hi = ((const int*)&hi4[m])[r];
          wv += bf2f(gtabh[j * P_ + hi]);
          local += wv * e;
        }
      }
    }
  }
  local = waveReduceSum(local);
  if (lane == 0) {
    atomicAdd(&sums[0], local);
    __threadfence();
    int done = atomicAdd((int*)sums + 2, 1);
    if (done == NJOBS - 1) {
      float tot = atomicAdd(&sums[0], 0.f);
      float pos = atomicAdd(&sums[1], 0.f);
      out[0] = logf(tot) - pos * (INVT / (float)B_);
    }
  }
}

extern "C" void kernel_launch(void* const* d_in, const int* in_sizes, int n_in,
                              void* d_out, int out_size, void* d_ws, size_t ws_size,
                              hipStream_t stream) {
  const float* x   = (const float*)d_in[0];
  const float* xa  = (const float*)d_in[1];
  const float* pw  = (const float*)d_in[2];
  const int* hq1   = (const int*)d_in[3];
  const int* hq2   = (const int*)d_in[4];
  const int* nq1   = (const int*)d_in[5];
  const int* nq2   = (const int*)d_in[6];
  float* out = (float*)d_out;

  char* ws = (char*)d_ws;
  __hip_bfloat16* outb  = (__hip_bfloat16*)(ws);               // 2,097,152 B
  unsigned short* gtabh = (unsigned short*)(ws + 2097152);     // 819,200 B
  float* pd    = (float*)(ws + 2916352);                       // 40,000 B
  int*   hq    = (int*)  (ws + 2956800);                       // 16,384 B
  int*   cnt   = (int*)  (ws + 2973184);                       // 400 B
  float* sums  = (float*)(ws + 2973696);                       // 16 B (2 accum + ticket)

  prep_kernel<<<613, 256, 0, stream>>>(x, xa, pw, hq1, hq2, hq, cnt, pd, outb, sums);
  gtab_kernel<<<N_ / 4, 256, 0, stream>>>(hq, cnt, pd, nq1, nq2, gtabh);
  tot_kernel<<<NJOBS, 64, 0, stream>>>(outb, gtabh, hq, sums, out);
}

// Round 5
// 131.714 us; speedup vs baseline: 1.2929x; 1.2929x over previous
//
#include <hip/hip_runtime.h>
#include <hip/hip_bf16.h>
#include <cstdint>

#define B_ 2048
#define N_ 4096
#define D_ 256
#define P_ 100
#define K_ 30
#define INVT 5.0f
#define NTILE 64                         // 64x64 wave tiles over N_=4096
#define NJOBS (NTILE * (NTILE + 1) / 2)  // 2080
#define NBLK (NJOBS / 4)                 // 520 blocks x 4 waves
#define NGRP 64

typedef __attribute__((ext_vector_type(8))) short bf16x8;
typedef __attribute__((ext_vector_type(4))) float f32x4;
typedef __attribute__((ext_vector_type(4))) unsigned short us4;

__device__ __forceinline__ float waveReduceSum(float v) {
#pragma unroll
  for (int off = 32; off > 0; off >>= 1) v += __shfl_xor(v, off, 64);
  return v;
}

__device__ __forceinline__ unsigned short f2bf(float f) {
  __hip_bfloat16 h = __float2bfloat16(f);
  return *reinterpret_cast<unsigned short*>(&h);
}
__device__ __forceinline__ float bf2f(unsigned short u) {
  return __uint_as_float(((unsigned int)u) << 16);
}

// control block layout (in ws): sums[0]=total, sums[1]=pos, ticket1, partial[64], ticket0[64]
struct Ctrl {
  float sums[2];
  int ticket1;
  int pad;
  float partial[NGRP];
  int ticket0[NGRP];
};

// ---- K1: block 0 = zero ctrl + hist/concat; 1..100 = proto_dist row; 101..612 = row-norm+pos ----
__global__ __launch_bounds__(256) void prep_kernel(
    const float* __restrict__ x, const float* __restrict__ xa, const float* __restrict__ pw,
    const int* __restrict__ hq1, const int* __restrict__ hq2, int* __restrict__ hq,
    int* __restrict__ cnt, float* __restrict__ pd, __hip_bfloat16* __restrict__ outb,
    Ctrl* __restrict__ ctrl) {
  __shared__ int c[P_];
  __shared__ float s4[4];
  int t = threadIdx.x, lane = t & 63, wv = t >> 6;
  int bx = blockIdx.x;
  if (bx == 0) {
    if (t < 2) ctrl->sums[t] = 0.f;
    if (t == 2) ctrl->ticket1 = 0;
    if (t < NGRP) { ctrl->partial[t] = 0.f; ctrl->ticket0[t] = 0; }
    if (t < P_) c[t] = 0;
    __syncthreads();
    for (int i = t; i < N_; i += 256) {
      int q = (i < B_) ? hq1[i] : hq2[i - B_];
      hq[i] = q;
      atomicAdd(&c[q], 1);
    }
    __syncthreads();
    if (t < P_) cnt[t] = c[t];
  } else if (bx <= P_) {
    int q = bx - 1;
    float4 aq = ((const float4*)(pw + q * D_))[lane];
    float ssq = waveReduceSum(aq.x * aq.x + aq.y * aq.y + aq.z * aq.z + aq.w * aq.w);
    float qinv = 1.f / fmaxf(sqrtf(ssq), 1e-12f);
    for (int r = wv; r < P_; r += 4) {
      float4 b = ((const float4*)(pw + r * D_))[lane];
      float s = aq.x * b.x + aq.y * b.y + aq.z * b.z + aq.w * b.w;
      float n = b.x * b.x + b.y * b.y + b.z * b.z + b.w * b.w;
      s = waveReduceSum(s);
      n = waveReduceSum(n);
      if (lane == 0) pd[q * P_ + r] = s * qinv / fmaxf(sqrtf(n), 1e-12f);
    }
  } else {
    int i = (bx - 101) * 4 + wv;
    float4 a = ((const float4*)(x + i * D_))[lane];
    float ss = waveReduceSum(a.x * a.x + a.y * a.y + a.z * a.z + a.w * a.w);
    float inv1 = 1.f / fmaxf(sqrtf(ss), 1e-12f);
    float o1x = a.x * inv1, o1y = a.y * inv1, o1z = a.z * inv1, o1w = a.w * inv1;
    us4 p1; p1[0] = f2bf(o1x); p1[1] = f2bf(o1y); p1[2] = f2bf(o1z); p1[3] = f2bf(o1w);
    ((us4*)(outb + i * D_))[lane] = p1;
    float4 b = ((const float4*)(xa + i * D_))[lane];
    float ss2 = waveReduceSum(b.x * b.x + b.y * b.y + b.z * b.z + b.w * b.w);
    float inv2 = 1.f / fmaxf(sqrtf(ss2), 1e-12f);
    float o2x = b.x * inv2, o2y = b.y * inv2, o2z = b.z * inv2, o2w = b.w * inv2;
    us4 p2; p2[0] = f2bf(o2x); p2[1] = f2bf(o2y); p2[2] = f2bf(o2z); p2[3] = f2bf(o2w);
    ((us4*)(outb + (B_ + i) * D_))[lane] = p2;
    float d = waveReduceSum(o1x * o2x + o1y * o2y + o1z * o2z + o1w * o2w);
    if (lane == 0) s4[wv] = d;
    __syncthreads();
    if (t == 0) atomicAdd(&ctrl->sums[1], s4[0] + s4[1] + s4[2] + s4[3]);
  }
}

// ---- K2: per-row Gtab[i][p] (bf16) = member ? reweight : 0 ----
__global__ void gtab_kernel(const int* __restrict__ hq, const int* __restrict__ cnt,
                            const float* __restrict__ pd, const int* __restrict__ nq1,
                            const int* __restrict__ nq2, unsigned short* __restrict__ gtabh) {
  __shared__ unsigned char memb[4][104];
  int wv = threadIdx.x >> 6, lane = threadIdx.x & 63;
  int i = blockIdx.x * 4 + wv;
  int q = hq[i];
  if (lane < 52) { memb[wv][lane * 2] = 0; memb[wv][lane * 2 + 1] = 0; }
  __syncthreads();
  const int* nrow = (i < B_) ? (nq1 + i * K_) : (nq2 + (i - B_) * K_);
  if (lane < K_) memb[wv][nrow[lane]] = 1;
  __syncthreads();

  int p0 = lane, p1 = lane + 64;
  bool has1 = (p1 < P_);
  float v0 = pd[q * P_ + p0];
  int m0 = cnt[p0] - (p0 == q ? 1 : 0);
  float v1 = 0.f; int m1 = 0;
  if (has1) { v1 = pd[q * P_ + p1]; m1 = cnt[p1] - (p1 == q ? 1 : 0); }

  float mn = 1e30f, mx = -1e30f;
  if (m0 > 0) { mn = fminf(mn, v0); mx = fmaxf(mx, v0); }
  if (has1 && m1 > 0) { mn = fminf(mn, v1); mx = fmaxf(mx, v1); }
#pragma unroll
  for (int off = 32; off > 0; off >>= 1) {
    mn = fminf(mn, __shfl_xor(mn, off, 64));
    mx = fmaxf(mx, __shfl_xor(mx, off, 64));
  }
  float rmin = fminf(0.f, mn);
  float rmax = fmaxf(rmin, mx);
  float inv = 1.f / (rmax - rmin);
  float r0 = (v0 - rmin) * inv, r1 = (v1 - rmin) * inv;
  float s1 = (m0 > 0 ? (float)m0 * r0 : 0.f) + ((has1 && m1 > 0) ? (float)m1 * r1 : 0.f);
  s1 = waveReduceSum(s1);
  float mu = s1 / (float)N_;
  float ss = (m0 > 0 ? (float)m0 * (r0 - mu) * (r0 - mu) : 0.f) +
             ((has1 && m1 > 0) ? (float)m1 * (r1 - mu) * (r1 - mu) : 0.f);
  ss = waveReduceSum(ss);
  ss += mu * mu;
  float var = ss / (float)(N_ - 1);
  float i2v = 1.f / (2.f * var);
  float g0 = memb[wv][p0] ? __expf((r0 - mu) * (r0 - mu) * i2v) : 0.f;
  gtabh[i * P_ + p0] = f2bf(g0);
  if (has1) {
    float g1 = memb[wv][p1] ? __expf((r1 - mu) * (r1 - mu) * i2v) : 0.f;
    gtabh[i * P_ + p1] = f2bf(g1);
  }
}

// ---- K3: 4 waves/block, one 64x64 triangle tile per wave, hierarchical completion ----
__global__ __launch_bounds__(256) void tot_kernel(
    const __hip_bfloat16* __restrict__ outb, const unsigned short* __restrict__ gtabh,
    const int* __restrict__ hq, Ctrl* __restrict__ ctrl, float* __restrict__ out) {
  __shared__ float s4[4];
  const int tid = threadIdx.x, lane = tid & 63, wid = tid >> 6;
  const int r16 = lane & 15, k8 = lane >> 4;

  // triangle decode: job -> (ti, tj), ti <= tj
  int rem = blockIdx.x * 4 + wid, ti = 0;
  while (rem >= NTILE - ti) { rem -= NTILE - ti; ++ti; }
  const int tj = ti + rem;
  const bool diag = (ti == tj);
  const int i0 = ti * 64, j0 = tj * 64;

  const __hip_bfloat16* Ab = outb + (i0 + r16) * D_ + k8 * 8;
  const __hip_bfloat16* Bb = outb + (j0 + r16) * D_ + k8 * 8;

  f32x4 acc[4][4] = {};
  bf16x8 a[2][4], b[2][4];
#pragma unroll
  for (int m = 0; m < 4; ++m) {
    a[0][m] = *(const bf16x8*)(Ab + m * 16 * D_);
    b[0][m] = *(const bf16x8*)(Bb + m * 16 * D_);
  }
#pragma unroll
  for (int kk = 0; kk < 8; ++kk) {
    const int cur = kk & 1, nxt = cur ^ 1;
    if (kk < 7) {
#pragma unroll
      for (int m = 0; m < 4; ++m) {
        a[nxt][m] = *(const bf16x8*)(Ab + m * 16 * D_ + (kk + 1) * 32);
        b[nxt][m] = *(const bf16x8*)(Bb + m * 16 * D_ + (kk + 1) * 32);
      }
    }
#pragma unroll
    for (int m = 0; m < 4; ++m)
#pragma unroll
      for (int n = 0; n < 4; ++n)
        acc[m][n] = __builtin_amdgcn_mfma_f32_16x16x32_bf16(a[cur][m], b[cur][n], acc[m][n], 0, 0, 0);
  }

  // epilogue: hq + weight gathers straight from L2-resident tables
  int4 hi4[4];
#pragma unroll
  for (int m = 0; m < 4; ++m) hi4[m] = *(const int4*)(hq + i0 + m * 16 + k8 * 4);
  int hj[4];
#pragma unroll
  for (int n = 0; n < 4; ++n) hj[n] = hq[j0 + n * 16 + r16];

  float local = 0.f;
  if (diag) {
#pragma unroll
    for (int m = 0; m < 4; ++m) {
#pragma unroll
      for (int n = 0; n < 4; ++n) {
#pragma unroll
        for (int r = 0; r < 4; ++r) {
          int il = m * 16 + k8 * 4 + r;
          int jl = n * 16 + r16;
          float e = __expf(acc[m][n][r] * INVT);
          float wv = bf2f(gtabh[(i0 + il) * P_ + hj[n]]);
          if (il != jl) local += wv * e;
        }
      }
    }
  } else {
#pragma unroll
    for (int m = 0; m < 4; ++m) {
#pragma unroll
      for (int n = 0; n < 4; ++n) {
#pragma unroll
        for (int r = 0; r < 4; ++r) {
          int i = i0 + m * 16 + k8 * 4 + r;
          int j = j0 + n * 16 + r16;
          float e = __expf(acc[m][n][r] * INVT);
          float wv = bf2f(gtabh[i * P_ + hj[n]]);
          int hi = ((const int*)&hi4[m])[r];
          wv += bf2f(gtabh[j * P_ + hi]);
          local += wv * e;
        }
      }
    }
  }
  local = waveReduceSum(local);
  if (lane == 0) s4[wid] = local;
  __syncthreads();
  if (tid == 0) {
    float blk = s4[0] + s4[1] + s4[2] + s4[3];
    const int g = blockIdx.x & (NGRP - 1);
    // level 0: accumulate into spread partial slot; force completion before ticket
    float old0 = atomicAdd(&ctrl->partial[g], blk);
    asm volatile("" ::"v"(old0));
    int cntg = (NBLK / NGRP) + (g < (NBLK & (NGRP - 1)) ? 1 : 0);
    int done0 = atomicAdd(&ctrl->ticket0[g], 1);
    if (done0 == cntg - 1) {
      // group winner: fold partial into global, then level-1 ticket
      float pg = atomicAdd(&ctrl->partial[g], 0.f);
      float old1 = atomicAdd(&ctrl->sums[0], pg);
      asm volatile("" ::"v"(old1));
      int done1 = atomicAdd(&ctrl->ticket1, 1);
      if (done1 == NGRP - 1) {
        float tot = atomicAdd(&ctrl->sums[0], 0.f);
        float pos = atomicAdd(&ctrl->sums[1], 0.f);
        out[0] = logf(tot) - pos * (INVT / (float)B_);
      }
    }
  }
}

extern "C" void kernel_launch(void* const* d_in, const int* in_sizes, int n_in,
                              void* d_out, int out_size, void* d_ws, size_t ws_size,
                              hipStream_t stream) {
  const float* x   = (const float*)d_in[0];
  const float* xa  = (const float*)d_in[1];
  const float* pw  = (const float*)d_in[2];
  const int* hq1   = (const int*)d_in[3];
  const int* hq2   = (const int*)d_in[4];
  const int* nq1   = (const int*)d_in[5];
  const int* nq2   = (const int*)d_in[6];
  float* out = (float*)d_out;

  char* ws = (char*)d_ws;
  __hip_bfloat16* outb  = (__hip_bfloat16*)(ws);               // 2,097,152 B
  unsigned short* gtabh = (unsigned short*)(ws + 2097152);     // 819,200 B
  float* pd    = (float*)(ws + 2916352);                       // 40,000 B
  int*   hq    = (int*)  (ws + 2956800);                       // 16,384 B
  int*   cnt   = (int*)  (ws + 2973184);                       // 400 B
  Ctrl*  ctrl  = (Ctrl*) (ws + 2973696);

  prep_kernel<<<613, 256, 0, stream>>>(x, xa, pw, hq1, hq2, hq, cnt, pd, outb, ctrl);
  gtab_kernel<<<N_ / 4, 256, 0, stream>>>(hq, cnt, pd, nq1, nq2, gtabh);
  tot_kernel<<<NBLK, 256, 0, stream>>>(outb, gtabh, hq, ctrl, out);
}